// Round 10
// baseline (163.945 us; speedup 1.0000x reference)
//
#include <hip/hip_runtime.h>
#include <float.h>

#define DEVI __device__ __forceinline__

namespace {

constexpr int NB   = 8;     // batch
constexpr int CD   = 256;   // dense channels
constexpr int CS   = 512;   // sparse channels
constexpr int MM   = 4096;  // dense points
constexpr int SS   = 1024;  // sparse points
constexpr int NN   = 4096;  // pcd points
constexpr int KTOT = 768;   // CD + CS
constexpr int OC   = 256;   // output channels
constexpr float KEPS  = 1e-8f;
constexpr float BNEPS = 1e-5f;
constexpr float SLOPE = 0.2f;

// ---------------- workspace layout (bytes) — total ~27.4 MB (ws = 256 MiB, verified) ----------------
constexpr size_t OFF_Z    = 0;                              // float [NB][SS][OC]  Z = W_s * sparse
constexpr size_t SZ_Z     = (size_t)NB * SS * OC * 4;       // 8,388,608
constexpr size_t OFF_RAW  = OFF_Z + SZ_Z;                   // bf16  [NB][OC][MM] raw pre-BN y
constexpr size_t SZ_RAW   = (size_t)NB * OC * MM * 2;       // 16,777,216
constexpr size_t OFF_IDX3 = OFF_RAW + SZ_RAW;               // int   [NB][MM][3]
constexpr size_t SZ_IDX3  = (size_t)NB * MM * 3 * 4;        // 393,216
constexpr size_t OFF_W3   = OFF_IDX3 + SZ_IDX3;             // float [NB][MM][3]
constexpr size_t OFF_WBF  = OFF_W3 + SZ_IDX3;               // bf16  [OC][KTOT]
constexpr size_t SZ_WBF   = (size_t)OC * KTOT * 2;          // 393,216
constexpr size_t OFF_PS   = OFF_WBF + SZ_WBF;               // float [OC][512] partial sums (transposed)
constexpr size_t SZ_PS    = (size_t)512 * OC * 4;           // 524,288
constexpr size_t OFF_PS2  = OFF_PS + SZ_PS;                 // float [OC][512] partial sumsq

typedef __attribute__((ext_vector_type(8))) short s16x8;
typedef __attribute__((ext_vector_type(8))) unsigned short u16x8;
typedef __attribute__((ext_vector_type(4))) float f32x4;

// float -> bf16 (RNE), returned as raw short
DEVI short f2bf(float f) {
  union { float f; unsigned u; } c; c.f = f;
  unsigned r = c.u + 0x7fffu + ((c.u >> 16) & 1u);
  return (short)(r >> 16);
}

DEVI unsigned umin_(unsigned a, unsigned b) { return a < b ? a : b; }
DEVI unsigned umax_(unsigned a, unsigned b) { return a > b ? a : b; }

// ---------------------------------------------------------------- KNN top-3 (+ conv_w cast prologue)
// Packed-key top-3 (key = (bits(d) & ~1023) | s).  2 dense points per lane so each
// sxyz LDS broadcast read is amortized over 2 distance evals (LDS-port was the
// bottleneck: 1024 ds_read_b128/block at ~12cyc each).  128 points per block.
__global__ __launch_bounds__(256) void k_knn(
    const int* __restrict__ didx, const int* __restrict__ sidx,
    const float* __restrict__ pcd,
    int* __restrict__ idx3, float* __restrict__ w3,
    float* __restrict__ outIdxF,
    const float* __restrict__ convw, short* __restrict__ wbf) {
  __shared__ float4   sxyz[SS];            // 16 KB candidate coords (+|s|^2 in .w)
  __shared__ unsigned pk[4][128][3];       // 6 KB partial top-3 packed keys

  int blk = blockIdx.x;                    // 8 * 32 = 256 blocks
  int b   = blk >> 5;
  int m0  = (blk & 31) << 7;               // 128-point tile
  int tid = threadIdx.x;
  const float* pb = pcd + (size_t)b * 3 * NN;

  // folded k_wcast: 256 blocks * 768 = 196608 = OC*KTOT exactly
  for (int i = tid; i < 768; i += 256) {
    int g = blk * 768 + i;
    wbf[g] = f2bf(convw[g]);
  }

  for (int s = tid; s < SS; s += 256) {
    int si = sidx[b * SS + s];
    float x = pb[si], yy = pb[NN + si], z = pb[2 * NN + si];
    sxyz[s] = make_float4(x, yy, z, x * x + yy * yy + z * z);
  }

  int p     = tid & 63;                    // lane's first point within tile
  int chunk = tid >> 6;                    // candidate chunk
  int mA    = m0 + p, mB = m0 + p + 64;
  int diA = didx[b * MM + mA], diB = didx[b * MM + mB];
  float pxA = pb[diA], pyA = pb[NN + diA], pzA = pb[2 * NN + diA];
  float pxB = pb[diB], pyB = pb[NN + diB], pzB = pb[2 * NN + diB];
  float ppA = pxA * pxA + pyA * pyA + pzA * pzA;
  float ppB = pxB * pxB + pyB * pyB + pzB * pzB;
  float nxA = -2.f * pxA, nyA = -2.f * pyA, nzA = -2.f * pzA;
  float nxB = -2.f * pxB, nyB = -2.f * pyB, nzB = -2.f * pzB;

  if (chunk == 0) {
    outIdxF[b * MM + mA] = (float)diA;     // output 1
    outIdxF[b * MM + mB] = (float)diB;
  }

  __syncthreads();

  unsigned a0 = 0xFFFFFFFFu, a1 = 0xFFFFFFFFu, a2 = 0xFFFFFFFFu;
  unsigned c0 = 0xFFFFFFFFu, c1 = 0xFFFFFFFFu, c2 = 0xFFFFFFFFu;
  int s0c = chunk << 8;
#pragma unroll 4
  for (int t = 0; t < 256; ++t) {
    int s = s0c + t;
    float4 c = sxyz[s];
    float dA = fmaf(nxA, c.x, c.w + ppA);
    dA = fmaf(nyA, c.y, dA);
    dA = fmaf(nzA, c.z, dA);
    dA = fmaxf(dA, 0.f);
    unsigned keyA = (__float_as_uint(dA) & 0xFFFFFC00u) | (unsigned)s;
    unsigned eA0 = umax_(keyA, a0); a0 = umin_(keyA, a0);
    unsigned eA1 = umax_(eA0, a1);  a1 = umin_(eA0, a1);
    a2 = umin_(eA1, a2);
    float dB = fmaf(nxB, c.x, c.w + ppB);
    dB = fmaf(nyB, c.y, dB);
    dB = fmaf(nzB, c.z, dB);
    dB = fmaxf(dB, 0.f);
    unsigned keyB = (__float_as_uint(dB) & 0xFFFFFC00u) | (unsigned)s;
    unsigned eB0 = umax_(keyB, c0); c0 = umin_(keyB, c0);
    unsigned eB1 = umax_(eB0, c1);  c1 = umin_(eB0, c1);
    c2 = umin_(eB1, c2);
  }
  pk[chunk][p][0] = a0;      pk[chunk][p][1] = a1;      pk[chunk][p][2] = a2;
  pk[chunk][p + 64][0] = c0; pk[chunk][p + 64][1] = c1; pk[chunk][p + 64][2] = c2;
  __syncthreads();

  if (tid < 128) {
    unsigned g0 = 0xFFFFFFFFu, g1 = 0xFFFFFFFFu, g2 = 0xFFFFFFFFu;
#pragma unroll
    for (int c = 0; c < 4; ++c)
#pragma unroll
      for (int r = 0; r < 3; ++r) {
        unsigned key = pk[c][tid][r];
        unsigned e0 = umax_(key, g0); g0 = umin_(key, g0);
        unsigned e1 = umax_(e0, g1);  g1 = umin_(e0, g1);
        g2 = umin_(e1, g2);
      }
    int j0 = g0 & 1023, j1 = g1 & 1023, j2 = g2 & 1023;
    float e0 = __uint_as_float(g0 & 0xFFFFFC00u);
    float e1 = __uint_as_float(g1 & 0xFFFFFC00u);
    float e2 = __uint_as_float(g2 & 0xFFFFFC00u);
    float w0 = 1.f / (e0 + KEPS), w1 = 1.f / (e1 + KEPS), w2 = 1.f / (e2 + KEPS);
    float inv = 1.f / (w0 + w1 + w2);
    int base = (b * MM + m0 + tid) * 3;
    idx3[base] = j0; idx3[base + 1] = j1; idx3[base + 2] = j2;
    w3[base] = w0 * inv; w3[base + 1] = w1 * inv; w3[base + 2] = w2 * inv;
  }
}

// ---------------------------------------------------------------- Z = W_s * sparse
// Z[b][s][o] = sum_c W[o][CD+c] * sp[b][c][s].  Tile: 32 s x 256 o, BK=64.
__global__ __launch_bounds__(256) void k_gemmZ(
    const float* __restrict__ sp, const short* __restrict__ wbf,
    float* __restrict__ Z) {
  __shared__ __align__(16) short Wl[256 * 72];   // [o][k] pad 64->72 (144B rows)
  __shared__ __align__(16) short Sl[32 * 72];    // [s][k] pad 64->72

  int blk = blockIdx.x;                 // 8 * 32 = 256 blocks
  int st = blk & 31, b = blk >> 5;
  int s0 = st * 32;
  int tid = threadIdx.x, wv = tid >> 6, lane = tid & 63;
  int lo = lane & 15, quad = lane >> 4;

  f32x4 acc[4][2] = {};
  for (int k0 = 0; k0 < CS; k0 += 64) {
    __syncthreads();
    // stage W_s slice [256][64] bf16 via b128
#pragma unroll
    for (int r = 0; r < 8; ++r) {
      int lin = r * 256 + tid, row = lin >> 3, c8 = lin & 7;
      uint4 v = *(const uint4*)((const unsigned short*)wbf + (size_t)row * KTOT + CD + k0 + c8 * 8);
      *(uint4*)(&Wl[row * 72 + c8 * 8]) = v;
    }
    // stage sp slice [64 c][32 s] -> Sl[s][c] (inline transpose + f32->bf16)
#pragma unroll
    for (int r = 0; r < 2; ++r) {
      int lin = r * 256 + tid, cc = lin >> 3, s4 = lin & 7;
      float4 v = *(const float4*)(sp + (size_t)(b * CS + k0 + cc) * SS + s0 + s4 * 4);
      Sl[(s4 * 4 + 0) * 72 + cc] = f2bf(v.x);
      Sl[(s4 * 4 + 1) * 72 + cc] = f2bf(v.y);
      Sl[(s4 * 4 + 2) * 72 + cc] = f2bf(v.z);
      Sl[(s4 * 4 + 3) * 72 + cc] = f2bf(v.w);
    }
    __syncthreads();
    s16x8 af[2][4], bfr[2][2];
#pragma unroll
    for (int h = 0; h < 2; ++h) {
#pragma unroll
      for (int i = 0; i < 4; ++i)
        af[h][i] = *(const s16x8*)(&Wl[(wv * 64 + i * 16 + lo) * 72 + h * 32 + quad * 8]);
#pragma unroll
      for (int j = 0; j < 2; ++j)
        bfr[h][j] = *(const s16x8*)(&Sl[(j * 16 + lo) * 72 + h * 32 + quad * 8]);
    }
#pragma unroll
    for (int h = 0; h < 2; ++h)
#pragma unroll
      for (int i = 0; i < 4; ++i)
#pragma unroll
        for (int j = 0; j < 2; ++j)
          acc[i][j] = __builtin_amdgcn_mfma_f32_16x16x32_bf16(af[h][i], bfr[h][j], acc[i][j], 0, 0, 0);
  }
  // write Z[b][s][o] — lane's 4 regs are 4 consecutive o -> float4 store
#pragma unroll
  for (int i = 0; i < 4; ++i)
#pragma unroll
    for (int j = 0; j < 2; ++j) {
      int s = j * 16 + lo, o = wv * 64 + i * 16 + quad * 4;
      *(f32x4*)(Z + (size_t)(b * SS + s0 + s) * OC + o) = acc[i][j];
    }
}

// ---------------------------------------------------------------- dense GEMM + combine + stats
// raw[b][o][m] (bf16) = sum_k W[o][k]*dense_bf[b][k][m] + sum_j w3[m][j]*Z[b][idx3[m][j]][o]
// Tile: 64 m x 256 o (full OC), 4 waves each 64o x 64m. K=256, BK=64 -> 4 steps.
// Stats from f32 values before quantization; partials written TRANSPOSED ps[o][blk]
// so k_norm can reduce a contiguous row (k_finalize eliminated).
__global__ __launch_bounds__(256) void k_gemmDC(
    const float* __restrict__ dense, const float* __restrict__ Z,
    const int* __restrict__ idx3, const float* __restrict__ w3,
    const short* __restrict__ wbf, unsigned short* __restrict__ raw,
    float* __restrict__ ps, float* __restrict__ ps2) {
  __shared__ __align__(16) short Wl[256 * 72];   // [o][k] pad 64->72; reused as P[32][260] f32
  __shared__ __align__(16) short Xl[64 * 72];    // [m][k] pad 64->72
  __shared__ int   mi3[192];
  __shared__ float mw3[192];

  int blk = blockIdx.x;                 // 8 * 64 = 512 blocks
  int mt = blk & 63, b = blk >> 6, m0 = mt << 6;
  int tid = threadIdx.x, wv = tid >> 6, lane = tid & 63;
  int lo = lane & 15, quad = lane >> 4;

  {
    int base = (b * MM + m0) * 3;
    for (int i = tid; i < 192; i += 256) { mi3[i] = idx3[base + i]; mw3[i] = w3[base + i]; }
  }

  f32x4 acc[4][4] = {};
  for (int k0 = 0; k0 < CD; k0 += 64) {
    __syncthreads();
    // stage W_d slice [256][64] bf16
#pragma unroll
    for (int r = 0; r < 8; ++r) {
      int lin = r * 256 + tid, row = lin >> 3, c8 = lin & 7;
      uint4 v = *(const uint4*)((const unsigned short*)wbf + (size_t)row * KTOT + k0 + c8 * 8);
      *(uint4*)(&Wl[row * 72 + c8 * 8]) = v;
    }
    // stage dense slice [64 k][64 m] -> Xl[m][k]: each thread loads 4 float4 along k,
    // packs ushort4 per m-row -> 4x ds_write_b64
    {
      int kk4 = tid >> 4, m4 = tid & 15;          // k-quad, m-quad
      float4 v0 = *(const float4*)(dense + (size_t)(b * CD + k0 + kk4 * 4 + 0) * MM + m0 + m4 * 4);
      float4 v1 = *(const float4*)(dense + (size_t)(b * CD + k0 + kk4 * 4 + 1) * MM + m0 + m4 * 4);
      float4 v2 = *(const float4*)(dense + (size_t)(b * CD + k0 + kk4 * 4 + 2) * MM + m0 + m4 * 4);
      float4 v3 = *(const float4*)(dense + (size_t)(b * CD + k0 + kk4 * 4 + 3) * MM + m0 + m4 * 4);
      ushort4 w;
      w.x = (unsigned short)f2bf(v0.x); w.y = (unsigned short)f2bf(v1.x);
      w.z = (unsigned short)f2bf(v2.x); w.w = (unsigned short)f2bf(v3.x);
      *(ushort4*)(&Xl[(m4 * 4 + 0) * 72 + kk4 * 4]) = w;
      w.x = (unsigned short)f2bf(v0.y); w.y = (unsigned short)f2bf(v1.y);
      w.z = (unsigned short)f2bf(v2.y); w.w = (unsigned short)f2bf(v3.y);
      *(ushort4*)(&Xl[(m4 * 4 + 1) * 72 + kk4 * 4]) = w;
      w.x = (unsigned short)f2bf(v0.z); w.y = (unsigned short)f2bf(v1.z);
      w.z = (unsigned short)f2bf(v2.z); w.w = (unsigned short)f2bf(v3.z);
      *(ushort4*)(&Xl[(m4 * 4 + 2) * 72 + kk4 * 4]) = w;
      w.x = (unsigned short)f2bf(v0.w); w.y = (unsigned short)f2bf(v1.w);
      w.z = (unsigned short)f2bf(v2.w); w.w = (unsigned short)f2bf(v3.w);
      *(ushort4*)(&Xl[(m4 * 4 + 3) * 72 + kk4 * 4]) = w;
    }
    __syncthreads();
    s16x8 af[2][4], bfr[2][4];
#pragma unroll
    for (int h = 0; h < 2; ++h) {
#pragma unroll
      for (int i = 0; i < 4; ++i)
        af[h][i] = *(const s16x8*)(&Wl[(wv * 64 + i * 16 + lo) * 72 + h * 32 + quad * 8]);
#pragma unroll
      for (int j = 0; j < 4; ++j)
        bfr[h][j] = *(const s16x8*)(&Xl[(j * 16 + lo) * 72 + h * 32 + quad * 8]);
    }
#pragma unroll
    for (int h = 0; h < 2; ++h)
#pragma unroll
      for (int i = 0; i < 4; ++i)
#pragma unroll
        for (int j = 0; j < 4; ++j)
          acc[i][j] = __builtin_amdgcn_mfma_f32_16x16x32_bf16(af[h][i], bfr[h][j], acc[i][j], 0, 0, 0);
  }

  // ---------------- epilogue: combine with interp projection, store bf16 raw, stats
  float* P = (float*)Wl;                 // [32][260] f32, pad 256->260
  const float* Zb = Z + (size_t)b * SS * OC;
  unsigned short* rb = raw + (size_t)b * OC * MM;
  float ss[4][4] = {}, s2s[4][4] = {};
  __syncthreads();                       // Wl MFMA reads done, safe to reuse as P

#pragma unroll
  for (int h = 0; h < 2; ++h) {
    // build P[ml][o] = sum_j w_j * Z[idx_j][o] for m-half h (coalesced 1KB-row reads)
#pragma unroll 4
    for (int ml = 0; ml < 32; ++ml) {
      int mg = (h * 32 + ml) * 3;
      float p = mw3[mg + 0] * Zb[(size_t)mi3[mg + 0] * OC + tid]
              + mw3[mg + 1] * Zb[(size_t)mi3[mg + 1] * OC + tid]
              + mw3[mg + 2] * Zb[(size_t)mi3[mg + 2] * OC + tid];
      P[ml * 260 + tid] = p;
    }
    __syncthreads();
#pragma unroll
    for (int i = 0; i < 4; ++i)
#pragma unroll
      for (int jj = 0; jj < 2; ++jj) {
        int j = h * 2 + jj, ml = jj * 16 + lo;
        int o = wv * 64 + i * 16 + quad * 4;
        f32x4 p = *(const f32x4*)(&P[ml * 260 + o]);
        f32x4 v = acc[i][j] + p;
        unsigned short* dst = rb + (size_t)o * MM + m0 + j * 16 + lo;
#pragma unroll
        for (int r = 0; r < 4; ++r) {
          float vv = v[r];
          dst[(size_t)r * MM] = (unsigned short)f2bf(vv);
          ss[i][r] += vv; s2s[i][r] += vv * vv;
        }
      }
    __syncthreads();
  }

  // reduce stats across the 16 m-lanes of each quad (deterministic), write partials
#pragma unroll
  for (int i = 0; i < 4; ++i)
#pragma unroll
    for (int r = 0; r < 4; ++r) {
      float a = ss[i][r], q = s2s[i][r];
      for (int off = 1; off < 16; off <<= 1) { a += __shfl_xor(a, off); q += __shfl_xor(q, off); }
      ss[i][r] = a; s2s[i][r] = q;
    }
  if (lo == 0) {
#pragma unroll
    for (int i = 0; i < 4; ++i)
#pragma unroll
      for (int r = 0; r < 4; ++r) {
        int o = wv * 64 + i * 16 + quad * 4 + r;
        ps[(size_t)o * 512 + blk]  = ss[i][r];   // transposed: [o][blk]
        ps2[(size_t)o * 512 + blk] = s2s[i][r];
      }
  }
}

// ---------------------------------------------------------------- BN finalize + apply + LeakyReLU
// one block per (b,o) row: reduce the channel's 512 partials (contiguous, L2-resident),
// compute fused scale/shift, then normalize the row (bf16 in, f32 out).
__global__ __launch_bounds__(256) void k_norm(
    const unsigned short* __restrict__ raw, float* __restrict__ y,
    const float* __restrict__ ps, const float* __restrict__ ps2,
    const float* __restrict__ gamma, const float* __restrict__ beta) {
  __shared__ float rw[8];
  __shared__ float sAB[2];
  int bo = blockIdx.x;                     // 8 * 256 = 2048 blocks
  int b = bo >> 8, o = bo & 255;
  int tid = threadIdx.x, wv = tid >> 6, lane = tid & 63;

  // reduce 512 partials (each thread owns 2)
  float s  = ps[(size_t)o * 512 + tid]  + ps[(size_t)o * 512 + 256 + tid];
  float s2 = ps2[(size_t)o * 512 + tid] + ps2[(size_t)o * 512 + 256 + tid];
#pragma unroll
  for (int off = 32; off; off >>= 1) { s += __shfl_down(s, off); s2 += __shfl_down(s2, off); }
  if (lane == 0) { rw[wv] = s; rw[4 + wv] = s2; }
  __syncthreads();
  if (tid == 0) {
    float S = rw[0] + rw[1] + rw[2] + rw[3];
    float S2 = rw[4] + rw[5] + rw[6] + rw[7];
    float mn = S / (float)(NB * MM);
    float vr = S2 / (float)(NB * MM) - mn * mn;
    float a  = rsqrtf(vr + BNEPS) * gamma[o];
    sAB[0] = a;
    sAB[1] = beta[o] - mn * a;
  }
  __syncthreads();
  float a = sAB[0], be = sAB[1];

  const unsigned short* row = raw + (size_t)(b * OC + o) * MM;
  float* dst = y + (size_t)(b * OC + o) * MM;
#pragma unroll
  for (int u = 0; u < 2; ++u) {
    int i = tid * 2 + u;                   // ushort8 index within row [0,512)
    u16x8 v = ((const u16x8*)row)[i];
    float out[8];
#pragma unroll
    for (int r = 0; r < 8; ++r) {
      union { unsigned u; float f; } c; c.u = ((unsigned)v[r]) << 16;
      float t = c.f * a + be;
      out[r] = t >= 0.f ? t : SLOPE * t;
    }
    float4* d4 = (float4*)(dst + (size_t)i * 8);
    d4[0] = make_float4(out[0], out[1], out[2], out[3]);
    d4[1] = make_float4(out[4], out[5], out[6], out[7]);
  }
}

}  // namespace

extern "C" void kernel_launch(void* const* d_in, const int* in_sizes, int n_in,
                              void* d_out, int out_size, void* d_ws, size_t ws_size,
                              hipStream_t stream) {
  const float* dense = (const float*)d_in[0];
  const int*   didx  = (const int*)d_in[1];
  const float* sp    = (const float*)d_in[2];
  const int*   sidx  = (const int*)d_in[3];
  const float* pcd   = (const float*)d_in[4];
  const float* convw = (const float*)d_in[5];
  const float* gamma = (const float*)d_in[6];
  const float* beta  = (const float*)d_in[7];

  float* y = (float*)d_out;                       // [8][256][4096] normalized output
  float* outIdxF = y + (size_t)NB * OC * MM;      // output 1: dense_idx as float

  char* ws = (char*)d_ws;                         // ~27.4 MB of 256 MiB
  float*          Z    = (float*)(ws + OFF_Z);
  unsigned short* raw  = (unsigned short*)(ws + OFF_RAW);
  int*            idx3 = (int*)(ws + OFF_IDX3);
  float*          w3   = (float*)(ws + OFF_W3);
  short*          wbf  = (short*)(ws + OFF_WBF);
  float*          ps   = (float*)(ws + OFF_PS);
  float*          ps2  = (float*)(ws + OFF_PS2);

  k_knn   <<<NB * (MM / 128), 256, 0, stream>>>(didx, sidx, pcd, idx3, w3, outIdxF, convw, wbf);
  k_gemmZ <<<NB * (SS / 32), 256, 0, stream>>>(sp, wbf, Z);
  k_gemmDC<<<NB * (MM / 64), 256, 0, stream>>>(dense, Z, idx3, w3, wbf, raw, ps, ps2);
  k_norm  <<<NB * OC, 256, 0, stream>>>(raw, y, ps, ps2, gamma, beta);
}